// Round 13
// baseline (16395.427 us; speedup 1.0000x reference)
//
#include <hip/hip_runtime.h>
#include <cstdint>
#include <cstddef>

#define SEQ   8192
#define HD    2048
#define IND   16
#define NBLK  256   // one block per CU; each owns 8 hidden units
#define NTHR  512   // 8 waves; wave w owns unit b*8+w (4 gate rows)
#define NSLOT 1024  // u64 slots per parity: lo32 = 2xfp16 h-pair, hi32 = tag
#define NXCD  8

// Gate: R14 showed 14 vs 24 ticks neutral -> T_vis ~850-1300cy; keep 16.
// R20 lesson: NO samples before the gate.
#define GATE_TICKS 16ull

typedef _Float16 h2  __attribute__((ext_vector_type(2)));
typedef unsigned u32x4 __attribute__((ext_vector_type(4)));

union paircvt { h2 v; unsigned u; };
union hcvt { _Float16 f; unsigned short u; };

__device__ __forceinline__ float fdot2f(h2 a, h2 b, float c) {
#if defined(__has_builtin)
#if __has_builtin(__builtin_amdgcn_fdot2)
    return __builtin_amdgcn_fdot2(a, b, c, false);
#else
    return c + (float)a.x * (float)b.x + (float)a.y * (float)b.y;
#endif
#else
    return c + (float)a.x * (float)b.x + (float)a.y * (float)b.y;
#endif
}

__device__ __forceinline__ float sigmoid_f(float x) {
    return 1.f / (1.f + __expf(-x));
}
__device__ __forceinline__ float tanh_f(float x) {
    float e = __expf(2.f * x);
    return 1.f - 2.f / (e + 1.f);
}

__device__ __forceinline__ unsigned my_xcd() {
    unsigned x;
    asm volatile("s_getreg_b32 %0, hwreg(HW_REG_XCC_ID, 0, 4)" : "=s"(x));
    return x & (NXCD - 1);
}

// ---- VALU cross-lane butterflies (pure: every lane gets the sum) ----
__device__ __forceinline__ float dpp_xor1(float x) {
    int i = __builtin_bit_cast(int, x);
    int r = __builtin_amdgcn_mov_dpp(i, 0xB1, 0xf, 0xf, false); // [1,0,3,2]
    return __builtin_bit_cast(float, r);
}
__device__ __forceinline__ float dpp_xor2(float x) {
    int i = __builtin_bit_cast(int, x);
    int r = __builtin_amdgcn_mov_dpp(i, 0x4E, 0xf, 0xf, false); // [2,3,0,1]
    return __builtin_bit_cast(float, r);
}
// row_ror:8 (ctrl 0x128): dest L reads (L+8)&15 within its 16-row = L^8.
__device__ __forceinline__ float dpp_ror8(float x) {
    int i = __builtin_bit_cast(int, x);
    int r = __builtin_amdgcn_mov_dpp(i, 0x128, 0xf, 0xf, false);
    return __builtin_bit_cast(float, r);
}
__device__ __forceinline__ float xor16_add(float x) {
    float a = x, b = x;
    asm volatile("v_permlane16_swap_b32 %0, %1" : "+v"(a), "+v"(b));
    return a + b;
}
__device__ __forceinline__ float xor32_add(float x) {
    float a = x, b = x;
    asm volatile("v_permlane32_swap_b32 %0, %1" : "+v"(a), "+v"(b));
    return a + b;
}

// Persistent LSTM, round 22: R21's 8-wave split with the in-flight-load
// REGISTER HAZARD closed. R21 failed correctness (absmax 2.4e-3, one
// phase showing 468): the staggered poll exits with a stale global_load
// still in flight targeting n's VGPRs; n was loop-local and dead after
// the break, so the allocator could reuse its physical registers for
// hv/p/sat temps -- the landing load then CORRUPTED live values (UB that
// R15-R19's 4-wave allocation happened to dodge). Fix:
//  - m, n hoisted OUT of the t-loop;
//  - poll-entry drain pins them: asm("s_waitcnt vmcnt(0)" : "+v"(m),
//    "+v"(n)) -- live ranges span the loop, so stale landings only ever
//    write m/n's dedicated registers, and the entry drain retires all
//    in-flight ops before new issues. Zero added stalls.
// (The m=n copy with A2 pending on m's regs is provably benign: A2's
// payload is bit-identical -- same slot, same step; no t+2 overwrite can
// precede our barrier#1(t) by the coverage+2-barrier safety argument.)
// All else identical to R21: one unit/wave, 64 fdot2/lane, butterfly
// tree with ONE DS stage, lane-local gates, 1-dwordx4 poll, coalesced
// hbuf publish (8 x 32B), raw lgkm-only barriers, gate=16.
__global__ __launch_bounds__(NTHR, 1) void lstm_persist(
    const float* __restrict__ sa,    // [SEQ, IND]
    const float* __restrict__ W_ih,  // [4*HD, IND]
    const float* __restrict__ W_hh,  // [4*HD, HD]
    const float* __restrict__ b_ih,  // [4*HD]
    const float* __restrict__ b_hh,  // [4*HD]
    unsigned long long* __restrict__ hrep,  // [NXCD][2][NSLOT] replicas
    _Float16* __restrict__ hs16)     // [SEQ, HD] h history (fp16)
{
    const int b   = blockIdx.x;
    const int tid = threadIdx.x;
    const int w   = tid >> 6;        // wave 0..7
    const int L   = tid & 63;        // lane
    const unsigned xcd = my_xcd();

    __shared__ h2 hh2[16 * 64];      // h_t pairs, XOR-swizzled [k][row^2k]
    __shared__ unsigned hbuf[8];     // per-wave fp16 h bits

    const int unit = b * 8 + w;      // this wave's hidden unit

    // ---- one-time: W_hh fragment -> registers (fp16 pairs) ----
    h2 wreg[4][16];
#pragma unroll
    for (int r = 0; r < 4; ++r) {
        const int row = r * HD + unit;
        const float4* Wr = (const float4*)(W_hh + (size_t)row * HD + L * 32);
#pragma unroll
        for (int q = 0; q < 8; ++q) {
            float4 f = Wr[q];
            h2 lo; lo.x = (_Float16)f.x; lo.y = (_Float16)f.y;
            h2 hi; hi.x = (_Float16)f.z; hi.y = (_Float16)f.w;
            wreg[r][2 * q]     = lo;
            wreg[r][2 * q + 1] = hi;
        }
    }
    // W_ih row + bias for gate (L&3); only lanes 0..3's xp seeds the tree
    const int rowL = (L & 3) * HD + unit;
    float wih[IND];
    {
        const float4* Wi = (const float4*)(W_ih + (size_t)rowL * IND);
#pragma unroll
        for (int q = 0; q < 4; ++q) {
            float4 f = Wi[q];
            wih[4 * q]     = f.x;
            wih[4 * q + 1] = f.y;
            wih[4 * q + 2] = f.z;
            wih[4 * q + 3] = f.w;
        }
    }
    const float bias = b_ih[rowL] + b_hh[rowL];

    // ---- hoisted LDS addresses (loop-invariant swizzle math) ----
    h2* wp0; h2* wp1;
    {
        const int pa = 2 * tid, pb = 2 * tid + 1;
        wp0 = &hh2[(pa & 15) * 64 + (((pa >> 4) ^ (2 * (pa & 15))) & 63)];
        wp1 = &hh2[(pb & 15) * 64 + (((pb >> 4) ^ (2 * (pb & 15))) & 63)];
    }
    const h2* rp[16];
#pragma unroll
    for (int k = 0; k < 16; ++k)
        rp[k] = &hh2[k * 64 + ((L ^ (2 * k)) & 63)];

    // x_t prefetch registers (depth 1)
    float sat[IND];
    {
        const float4* s4 = (const float4*)(sa);
#pragma unroll
        for (int q = 0; q < 4; ++q) {
            float4 f = s4[q];
            sat[4 * q]     = f.x;
            sat[4 * q + 1] = f.y;
            sat[4 * q + 2] = f.z;
            sat[4 * q + 3] = f.w;
        }
    }

    float c = 0.f;                   // cell state (redundant across lanes)
    unsigned long long pubclk = 0;

    // Poll registers: LOOP-SPANNING lifetime (the hazard fix). Stale
    // staggered loads may land any time before the next entry drain;
    // with m/n pinned they can only ever write these dedicated regs.
    u32x4 m = {0, 0, 0, 0}, n = {0, 0, 0, 0};

    for (unsigned t = 0; t < SEQ; ++t) {
        // ---- xp from prefetched x_t (no serial load stall) ----
        float xp = bias;
#pragma unroll
        for (int k = 0; k < IND; ++k) xp += sat[k] * wih[k];

        // ---- issue x_{t+1} prefetch PRE-GATE: retires under gate+poll ----
        if (t + 1 < SEQ) {
            const float4* s4 = (const float4*)(sa + (size_t)(t + 1) * IND);
#pragma unroll
            for (int q = 0; q < 4; ++q) {
                float4 f = s4[q];
                sat[4 * q]     = f.x;
                sat[4 * q + 1] = f.y;
                sat[4 * q + 2] = f.z;
                sat[4 * q + 3] = f.w;
            }
        }

        // ---- clock gate: no LLC polls before own-publish + min flight ----
        if (t) {
            unsigned long long now;
            do {
                now = __builtin_amdgcn_s_memrealtime();
            } while (now - pubclk < GATE_TICKS);
        }

        // ---- staggered double-buffered poll: ONE dwordx4 per thread ----
        const unsigned pin = t & 1;
        const uint32_t* pp =
            (const uint32_t*)(hrep + ((size_t)xcd * 2 + pin) * NSLOT)
            + 4 * tid;
        // entry drain PINS m,n (keeps their registers allocated across
        // the whole loop) and retires stale loads + store-acks + sat.
        asm volatile("s_waitcnt vmcnt(0)"
                     : "+v"(m), "+v"(n) :: "memory");
        asm volatile(
            "global_load_dwordx4 %0, %1, off sc1"
            : "=v"(m) : "v"(pp) : "memory");
        int tries = 0;
        for (;;) {
            asm volatile(
                "global_load_dwordx4 %0, %1, off sc1"
                : "=v"(n) : "v"(pp) : "memory");
            asm volatile("s_waitcnt vmcnt(1)" : "+v"(m) :: "memory");
            if ((m.y == t) & (m.w == t)) break;   // n stays in flight
            asm volatile(
                "global_load_dwordx4 %0, %1, off sc1"
                : "=v"(m) : "v"(pp) : "memory");
            asm volatile("s_waitcnt vmcnt(1)" : "+v"(n) :: "memory");
            if ((n.y == t) & (n.w == t)) { m = n; break; }  // m in flight
            if (++tries > 8) __builtin_amdgcn_s_sleep(1);
        }

        // ---- stage 2 pairs into swizzled LDS (<=2-way = free) ----
        {
            paircvt cv;
            cv.u = m.x; *wp0 = cv.v;
            cv.u = m.z; *wp1 = cv.v;
        }
        // RAW barrier #1: order only LDS staging (lgkmcnt), NOT vmcnt --
        // stale poll loads retire under the dots into pinned m/n regs.
        asm volatile("s_waitcnt lgkmcnt(0)" ::: "memory");
        __builtin_amdgcn_s_barrier();

        // ---- read this lane's 16 pairs (cols [32L, 32L+32)) ----
        h2 hv[16];
#pragma unroll
        for (int k = 0; k < 16; ++k)
            hv[k] = *rp[k];

        // ---- 4 gate rows x 32 cols; xp seeded at the tree leaf ----
        float p0 = (L == 0) ? xp : 0.f;
        float p1 = (L == 1) ? xp : 0.f;
        float p2 = (L == 2) ? xp : 0.f;
        float p3 = (L == 3) ? xp : 0.f;
#pragma unroll
        for (int k = 0; k < 16; ++k) {
            p0 = fdot2f(wreg[0][k], hv[k], p0);
            p1 = fdot2f(wreg[1][k], hv[k], p1);
            p2 = fdot2f(wreg[2][k], hv[k], p2);
            p3 = fdot2f(wreg[3][k], hv[k], p3);
        }

        // ---- full butterfly tree: ONE DS stage (xor4), rest VALU ----
        p0 += dpp_xor1(p0); p1 += dpp_xor1(p1);
        p2 += dpp_xor1(p2); p3 += dpp_xor1(p3);
        p0 += dpp_xor2(p0); p1 += dpp_xor2(p1);
        p2 += dpp_xor2(p2); p3 += dpp_xor2(p3);
        p0 += __shfl_xor(p0, 4, 64); p1 += __shfl_xor(p1, 4, 64);
        p2 += __shfl_xor(p2, 4, 64); p3 += __shfl_xor(p3, 4, 64);
        p0 += dpp_ror8(p0); p1 += dpp_ror8(p1);
        p2 += dpp_ror8(p2); p3 += dpp_ror8(p3);
        p0 = xor16_add(p0); p1 = xor16_add(p1);
        p2 = xor16_add(p2); p3 = xor16_add(p3);
        p0 = xor32_add(p0); p1 = xor32_add(p1);
        p2 = xor32_add(p2); p3 = xor32_add(p3);

        // ---- gates: fully lane-local (PyTorch order i,f,g,o) ----
        float ii = sigmoid_f(p0);
        float ff = sigmoid_f(p1);
        float g  = tanh_f(p2);
        float oo = sigmoid_f(p3);
        c = ff * c + ii * g;
        float h = oo * tanh_f(c);   // identical on all 64 lanes

        // ---- deposit h bits; assemble + publish coalesced ----
        const unsigned pout = (t + 1) & 1;
        {
            hcvt hc; hc.f = (_Float16)h;
            if (L == 0) hbuf[w] = (unsigned)hc.u;
        }
        // barrier #2: gather the 8 h values (lgkm-only, raw)
        asm volatile("s_waitcnt lgkmcnt(0)" ::: "memory");
        __builtin_amdgcn_s_barrier();
        if (w < 2) {
            // wave w stores replicas 4w..4w+3; lanes 0..15: replica
            // 4w+(L>>2), slot b*4+(L&3). 4 adjacent lanes per replica =
            // one coalesced 32B transaction (4 per wave, 8 total).
            __builtin_amdgcn_s_setprio(1);
            const int s = L & 3;
            unsigned pk = (hbuf[2 * s] & 0xffffu) | (hbuf[2 * s + 1] << 16);
            unsigned long long msg =
                ((unsigned long long)(t + 1) << 32) | (unsigned long long)pk;
            if (L < 16)
                __hip_atomic_store(
                    &hrep[((size_t)(4 * w + (L >> 2)) * 2 + pout) * NSLOT
                          + (size_t)b * 4 + s], msg,
                    __ATOMIC_RELAXED, __HIP_MEMORY_SCOPE_AGENT);
            __builtin_amdgcn_s_setprio(0);
        } else if (w == 2) {
            // non-critical history write: lanes 0..3, coalesced 16B
            if (L < 4) {
                unsigned pk =
                    (hbuf[2 * L] & 0xffffu) | (hbuf[2 * L + 1] << 16);
                ((unsigned*)hs16)[(size_t)t * (HD / 2) + b * 4 + L] = pk;
            }
        }
        pubclk = __builtin_amdgcn_s_memrealtime();
    }
}

// Output projection: out[t,0:3] = hs[t]·W_uvw^T + b_uvw,
//                    out[t,3:6] = hs[t]·W_pqr^T + b_pqr
__global__ __launch_bounds__(256) void out_proj_kernel(
    const _Float16* __restrict__ hs16,
    const float* __restrict__ W_uvw, const float* __restrict__ b_uvw,
    const float* __restrict__ W_pqr, const float* __restrict__ b_pqr,
    float* __restrict__ out)
{
    __shared__ float Ws[6 * HD];
    const int tid = threadIdx.x;
    for (int i = tid; i < 3 * HD; i += 256) Ws[i] = W_uvw[i];
    for (int i = tid; i < 3 * HD; i += 256) Ws[3 * HD + i] = W_pqr[i];
    __syncthreads();

    const int w = tid >> 6, L = tid & 63;
#pragma unroll
    for (int r = 0; r < 4; ++r) {
        const int t = blockIdx.x * 16 + w * 4 + r;
        const _Float16* hrow = hs16 + (size_t)t * HD;
        float acc[6] = {0.f, 0.f, 0.f, 0.f, 0.f, 0.f};
        for (int cidx = L; cidx < HD; cidx += 64) {
            float hval = (float)hrow[cidx];
#pragma unroll
            for (int j = 0; j < 6; ++j) acc[j] += hval * Ws[j * HD + cidx];
        }
#pragma unroll
        for (int j = 0; j < 6; ++j) {
#pragma unroll
            for (int d = 1; d < 64; d <<= 1)
                acc[j] += __shfl_xor(acc[j], d, 64);
        }
        if (L == 0) {
#pragma unroll
            for (int j = 0; j < 6; ++j)
                out[(size_t)t * 6 + j] =
                    acc[j] + (j < 3 ? b_uvw[j] : b_pqr[j - 3]);
        }
    }
}

extern "C" void kernel_launch(void* const* d_in, const int* in_sizes, int n_in,
                              void* d_out, int out_size, void* d_ws, size_t ws_size,
                              hipStream_t stream) {
    (void)in_sizes; (void)n_in; (void)out_size; (void)ws_size;

    const float* sa    = (const float*)d_in[0];
    const float* W_ih  = (const float*)d_in[1];
    const float* W_hh  = (const float*)d_in[2];
    const float* b_ih  = (const float*)d_in[3];
    const float* b_hh  = (const float*)d_in[4];
    const float* W_uvw = (const float*)d_in[5];
    const float* b_uvw = (const float*)d_in[6];
    const float* W_pqr = (const float*)d_in[7];
    const float* b_pqr = (const float*)d_in[8];
    float* out = (float*)d_out;

    // workspace: [hs16: 32 MB][hrep: NXCD*2*NSLOT*8 = 128 KB]
    char* ws = (char*)d_ws;
    _Float16* hs16 = (_Float16*)ws;
    unsigned long long* hrep =
        (unsigned long long*)(ws + (size_t)SEQ * HD * 2);

    // zero replicas: tag 0 == "h_0 = 0 is ready" in every copy
    hipMemsetAsync(hrep, 0, (size_t)NXCD * 2 * NSLOT * 8, stream);

    hipLaunchKernelGGL(lstm_persist, dim3(NBLK), dim3(NTHR), 0, stream,
                       sa, W_ih, W_hh, b_ih, b_hh, hrep, hs16);
    hipLaunchKernelGGL(out_proj_kernel, dim3(SEQ / 16), dim3(256), 0, stream,
                       hs16, W_uvw, b_uvw, W_pqr, b_pqr, out);
}

// Round 14
// 13617.014 us; speedup vs baseline: 1.2040x; 1.2040x over previous
//
#include <hip/hip_runtime.h>
#include <cstdint>
#include <cstddef>

#define SEQ   8192
#define HD    2048
#define IND   16
#define NBLK  256   // one block per CU; each owns 8 hidden units
#define NTHR  256   // 4 waves; wave w owns units {b*8+2w, b*8+2w+1} = 8 rows
#define NSLOT 1024  // u64 slots per parity: lo32 = 2xfp16 h-pair, hi32 = tag
#define NXCD  8

// Gate: R14 showed 14 vs 24 ticks neutral -> T_vis ~850-1300cy; keep 16.
#define GATE_TICKS 16ull

typedef _Float16 h2  __attribute__((ext_vector_type(2)));
typedef unsigned u32x4 __attribute__((ext_vector_type(4)));

union paircvt { h2 v; unsigned u; };

__device__ __forceinline__ float fdot2f(h2 a, h2 b, float c) {
#if defined(__has_builtin)
#if __has_builtin(__builtin_amdgcn_fdot2)
    return __builtin_amdgcn_fdot2(a, b, c, false);
#else
    return c + (float)a.x * (float)b.x + (float)a.y * (float)b.y;
#endif
#else
    return c + (float)a.x * (float)b.x + (float)a.y * (float)b.y;
#endif
}

__device__ __forceinline__ float sigmoid_f(float x) {
    return 1.f / (1.f + __expf(-x));
}
__device__ __forceinline__ float tanh_f(float x) {
    float e = __expf(2.f * x);
    return 1.f - 2.f / (e + 1.f);
}

__device__ __forceinline__ unsigned my_xcd() {
    unsigned x;
    asm volatile("s_getreg_b32 %0, hwreg(HW_REG_XCC_ID, 0, 4)" : "=s"(x));
    return x & (NXCD - 1);
}

// ---- VALU cross-lane primitives (replace DS-pipe shuffles) ----
__device__ __forceinline__ float dpp_xor1(float x) {
    int i = __builtin_bit_cast(int, x);
    int r = __builtin_amdgcn_mov_dpp(i, 0xB1, 0xf, 0xf, false); // [1,0,3,2]
    return __builtin_bit_cast(float, r);
}
__device__ __forceinline__ float dpp_xor2(float x) {
    int i = __builtin_bit_cast(int, x);
    int r = __builtin_amdgcn_mov_dpp(i, 0x4E, 0xf, 0xf, false); // [2,3,0,1]
    return __builtin_bit_cast(float, r);
}
// row_ror:8 (ctrl 0x128): within each 16-lane row, dest L reads (L+8)&15,
// which equals L^8 -- an exact xor-8 exchange on the VALU pipe.
__device__ __forceinline__ float dpp_ror8(float x) {
    int i = __builtin_bit_cast(int, x);
    int r = __builtin_amdgcn_mov_dpp(i, 0x128, 0xf, 0xf, false);
    return __builtin_bit_cast(float, r);
}
__device__ __forceinline__ float xor16_add(float x) {
    float a = x, b = x;
    asm volatile("v_permlane16_swap_b32 %0, %1" : "+v"(a), "+v"(b));
    return a + b;
}
__device__ __forceinline__ float xor32_add(float x) {
    float a = x, b = x;
    asm volatile("v_permlane32_swap_b32 %0, %1" : "+v"(a), "+v"(b));
    return a + b;
}

// Persistent LSTM, round 23: EXACT REVERT to R19 (13.46ms, best verified).
// R22 post-mortem closed the 8-wave question: even hazard-fixed and with
// coalesced publish + VALU tree, one-unit-per-wave lost 2.9ms (VALUBusy
// 31.7->41.6%: 2x redundant butterfly work + 8-wave barrier coupling).
// Two independent attempts (R11, R22) both lost >=2.9ms -> the 4-wave /
// 2-units-per-wave decomposition is structurally final for this problem.
// Lever classes probed across the session: consumer sampling (R15 +1.4%),
// gate timing (R14 neutral), compute tail (R13/R17 hidden), store path
// (R18/R19 -6.4%, real), poll topology (R16 -10%), wave split (R11/R22
// -20%), pre-gate sampling (R20 -19%). Residual ~3870cy/step = LLC
// store->load visibility (~1000cy HW) + discovery quantization (~300cy,
// minimized) + exposed tail (~1000cy, minimized) + 256-block straggler
// max (~800cy, inherent to all-to-all x 8192 steps).
__global__ __launch_bounds__(NTHR, 1) void lstm_persist(
    const float* __restrict__ sa,    // [SEQ, IND]
    const float* __restrict__ W_ih,  // [4*HD, IND]
    const float* __restrict__ W_hh,  // [4*HD, HD]
    const float* __restrict__ b_ih,  // [4*HD]
    const float* __restrict__ b_hh,  // [4*HD]
    unsigned long long* __restrict__ hrep,  // [NXCD][2][NSLOT] replicas
    _Float16* __restrict__ hs16)     // [SEQ, HD] h history (fp16)
{
    const int b   = blockIdx.x;
    const int tid = threadIdx.x;
    const int w   = tid >> 6;        // wave 0..3
    const int L   = tid & 63;        // lane
    const unsigned xcd = my_xcd();

    __shared__ h2 hh2[16 * 64];      // h_t pairs, XOR-swizzled [k][row^2k]
    __shared__ unsigned long long pkbuf[4];   // per-wave packed messages

    const int ubase = b * 8 + 2 * w; // first of this wave's 2 units

    // ---- one-time: W_hh fragment -> registers (fp16 pairs) ----
    h2 wreg[8][16];
#pragma unroll
    for (int r = 0; r < 8; ++r) {
        const int row = (r & 3) * HD + ubase + (r >> 2);
        const float4* Wr = (const float4*)(W_hh + (size_t)row * HD + L * 32);
#pragma unroll
        for (int q = 0; q < 8; ++q) {
            float4 f = Wr[q];
            h2 lo; lo.x = (_Float16)f.x; lo.y = (_Float16)f.y;
            h2 hi; hi.x = (_Float16)f.z; hi.y = (_Float16)f.w;
            wreg[r][2 * q]     = lo;
            wreg[r][2 * q + 1] = hi;
        }
    }
    // W_ih row + bias; row map (R17): gate = L&3, unit = (L>>3)&1
    const int rowL = (L & 3) * HD + ubase + ((L >> 3) & 1);
    float wih[IND];
    {
        const float4* Wi = (const float4*)(W_ih + (size_t)rowL * IND);
#pragma unroll
        for (int q = 0; q < 4; ++q) {
            float4 f = Wi[q];
            wih[4 * q]     = f.x;
            wih[4 * q + 1] = f.y;
            wih[4 * q + 2] = f.z;
            wih[4 * q + 3] = f.w;
        }
    }
    const float bias = b_ih[rowL] + b_hh[rowL];

    // ---- hoisted LDS addresses (loop-invariant swizzle math) ----
    h2* wp0; h2* wp1; h2* wp2; h2* wp3;
    {
        const int pa = 2 * tid, pb = 2 * tid + 1;
        const int pc = 512 + 2 * tid, pd = 513 + 2 * tid;
        wp0 = &hh2[(pa & 15) * 64 + (((pa >> 4) ^ (2 * (pa & 15))) & 63)];
        wp1 = &hh2[(pb & 15) * 64 + (((pb >> 4) ^ (2 * (pb & 15))) & 63)];
        wp2 = &hh2[(pc & 15) * 64 + (((pc >> 4) ^ (2 * (pc & 15))) & 63)];
        wp3 = &hh2[(pd & 15) * 64 + (((pd >> 4) ^ (2 * (pd & 15))) & 63)];
    }
    const h2* rp[16];
#pragma unroll
    for (int k = 0; k < 16; ++k)
        rp[k] = &hh2[k * 64 + ((L ^ (2 * k)) & 63)];

    // x_t prefetch registers (depth 1)
    float sat[IND];
    {
        const float4* s4 = (const float4*)(sa);
#pragma unroll
        for (int q = 0; q < 4; ++q) {
            float4 f = s4[q];
            sat[4 * q]     = f.x;
            sat[4 * q + 1] = f.y;
            sat[4 * q + 2] = f.z;
            sat[4 * q + 3] = f.w;
        }
    }

    // cell state: lanes with (L&8)==0 hold c of unit0, (L&8)==8 -> unit1
    float c = 0.f;
    unsigned long long pubclk = 0;

    for (unsigned t = 0; t < SEQ; ++t) {
        // ---- xp from prefetched x_t (no serial load stall) ----
        float xp = bias;
#pragma unroll
        for (int k = 0; k < IND; ++k) xp += sat[k] * wih[k];

        // ---- issue x_{t+1} prefetch PRE-GATE: retires under gate+poll ----
        if (t + 1 < SEQ) {
            const float4* s4 = (const float4*)(sa + (size_t)(t + 1) * IND);
#pragma unroll
            for (int q = 0; q < 4; ++q) {
                float4 f = s4[q];
                sat[4 * q]     = f.x;
                sat[4 * q + 1] = f.y;
                sat[4 * q + 2] = f.z;
                sat[4 * q + 3] = f.w;
            }
        }

        // ---- clock gate: no LLC polls before own-publish + min flight ----
        if (t) {
            unsigned long long now;
            do {
                now = __builtin_amdgcn_s_memrealtime();
            } while (now - pubclk < GATE_TICKS);
        }

        // ---- staggered double-buffered poll of own-XCD replica ----
        const unsigned pin = t & 1;
        const uint32_t* base =
            (const uint32_t*)(hrep + ((size_t)xcd * 2 + pin) * NSLOT);
        const uint32_t* pp0 = base + 4 * tid;
        const uint32_t* pp1 = base + 1024 + 4 * tid;
        u32x4 m0, m1, n0, n1;
        asm volatile("s_waitcnt vmcnt(0)" ::: "memory");
        asm volatile(
            "global_load_dwordx4 %0, %2, off sc1\n\t"
            "global_load_dwordx4 %1, %3, off sc1"
            : "=v"(m0), "=v"(m1) : "v"(pp0), "v"(pp1) : "memory");
        int tries = 0;
        for (;;) {
            asm volatile(
                "global_load_dwordx4 %0, %2, off sc1\n\t"
                "global_load_dwordx4 %1, %3, off sc1"
                : "=v"(n0), "=v"(n1) : "v"(pp0), "v"(pp1) : "memory");
            asm volatile("s_waitcnt vmcnt(2)"
                         : "+v"(m0), "+v"(m1) :: "memory");
            if ((m0.y == t) & (m0.w == t) & (m1.y == t) & (m1.w == t))
                break;
            asm volatile(
                "global_load_dwordx4 %0, %2, off sc1\n\t"
                "global_load_dwordx4 %1, %3, off sc1"
                : "=v"(m0), "=v"(m1) : "v"(pp0), "v"(pp1) : "memory");
            asm volatile("s_waitcnt vmcnt(2)"
                         : "+v"(n0), "+v"(n1) :: "memory");
            if ((n0.y == t) & (n0.w == t) & (n1.y == t) & (n1.w == t)) {
                m0 = n0; m1 = n1;
                break;
            }
            if (++tries > 8) __builtin_amdgcn_s_sleep(1);
        }

        // ---- stage 4 pairs into swizzled LDS (<=2-way = free) ----
        {
            paircvt cv;
            cv.u = m0.x; *wp0 = cv.v;
            cv.u = m0.z; *wp1 = cv.v;
            cv.u = m1.x; *wp2 = cv.v;
            cv.u = m1.z; *wp3 = cv.v;
        }
        // RAW barrier #1: order only the LDS staging (lgkmcnt), NOT vmcnt.
        asm volatile("s_waitcnt lgkmcnt(0)" ::: "memory");
        __builtin_amdgcn_s_barrier();

        // ---- read this lane's 16 pairs (cols [32L, 32L+32)) ----
        h2 hv[16];
#pragma unroll
        for (int k = 0; k < 16; ++k)
            hv[k] = *rp[k];

        // ---- 8 rows x 32 cols of dot product per lane ----
        float p[8] = {0.f, 0.f, 0.f, 0.f, 0.f, 0.f, 0.f, 0.f};
#pragma unroll
        for (int r = 0; r < 8; ++r)
#pragma unroll
            for (int k = 0; k < 16; ++k)
                p[r] = fdot2f(wreg[r][k], hv[k], p[r]);

        // ---- merge-reduce, dims {1,2,8} on VALU; d=4 pure-reduce on DS ----
        const bool h1 = (L & 1), h2b = (L & 2), h8 = (L & 8);
        float v0, v1, v2, v3;
        {
            float k0 = h1 ? p[1] : p[0], s0 = h1 ? p[0] : p[1];
            v0 = k0 + dpp_xor1(s0);
            float k1 = h1 ? p[3] : p[2], s1 = h1 ? p[2] : p[3];
            v1 = k1 + dpp_xor1(s1);
            float k2 = h1 ? p[5] : p[4], s2 = h1 ? p[4] : p[5];
            v2 = k2 + dpp_xor1(s2);
            float k3 = h1 ? p[7] : p[6], s3 = h1 ? p[6] : p[7];
            v3 = k3 + dpp_xor1(s3);
        }
        float w0, w1;
        {
            float k0 = h2b ? v1 : v0, s0 = h2b ? v0 : v1;
            w0 = k0 + dpp_xor2(s0);
            float k1 = h2b ? v3 : v2, s1 = h2b ? v2 : v3;
            w1 = k1 + dpp_xor2(s1);
        }
        float tot;
        {
            float k0 = h8 ? w1 : w0, s0 = h8 ? w0 : w1;
            tot = k0 + dpp_ror8(s0);          // d=8 merge on VALU
        }
        tot += __shfl_xor(tot, 4, 64);        // d=4 pure reduction (DS)
        tot = xor16_add(tot);
        tot = xor32_add(tot);
        tot += xp;

        // ---- gates: width-16 gathers from lanes {(L&8)+r} ----
        const int ub8 = L & 8;   // 0 -> unit0 rows on lanes 0..3, 8 -> unit1
        float gi = __shfl(tot, ub8 + 0, 16);
        float gf = __shfl(tot, ub8 + 1, 16);
        float gg = __shfl(tot, ub8 + 2, 16);
        float go = __shfl(tot, ub8 + 3, 16);
        float ii = sigmoid_f(gi);
        float ff = sigmoid_f(gf);
        float g  = tanh_f(gg);
        float oo = sigmoid_f(go);
        c = ff * c + ii * g;
        float h = oo * tanh_f(c);

        // ---- pack via DPP (no DS): lane0 has unit0 h; ror8 brings unit1 ----
        const unsigned pout = (t + 1) & 1;
        {
            float hO = dpp_ror8(h);       // lane 0 <- lane 8's h (unit1)
            paircvt pk;
            pk.v.x = (_Float16)h;         // valid on lane 0 (unit ubase)
            pk.v.y = (_Float16)hO;        // unit ubase+1
            unsigned long long msg =
                ((unsigned long long)(t + 1) << 32) | (unsigned long long)pk.u;
            if (L == 0) pkbuf[w] = msg;   // deposit wave's message
        }
        // barrier #2: gather the 4 messages (lgkm-only, raw)
        asm volatile("s_waitcnt lgkmcnt(0)" ::: "memory");
        __builtin_amdgcn_s_barrier();
        if (w < 2) {
            // wave w stores replicas 4w..4w+3; lanes 0..15: replica
            // 4w+(L>>2), slot b*4+(L&3). 4 adjacent lanes per replica =
            // one coalesced 32B transaction (4 per wave, 8 total).
            __builtin_amdgcn_s_setprio(1);
            unsigned long long m = pkbuf[L & 3];
            if (L < 16)
                __hip_atomic_store(
                    &hrep[((size_t)(4 * w + (L >> 2)) * 2 + pout) * NSLOT
                          + (size_t)b * 4 + (L & 3)], m,
                    __ATOMIC_RELAXED, __HIP_MEMORY_SCOPE_AGENT);
            __builtin_amdgcn_s_setprio(0);
        } else if (w == 2) {
            // non-critical history write: lanes 0..3, coalesced 16B
            if (L < 4)
                ((unsigned*)hs16)[(size_t)t * (HD / 2) + b * 4 + L] =
                    (unsigned)pkbuf[L];
        }
        pubclk = __builtin_amdgcn_s_memrealtime();
    }
}

// Output projection: out[t,0:3] = hs[t]·W_uvw^T + b_uvw,
//                    out[t,3:6] = hs[t]·W_pqr^T + b_pqr
__global__ __launch_bounds__(256) void out_proj_kernel(
    const _Float16* __restrict__ hs16,
    const float* __restrict__ W_uvw, const float* __restrict__ b_uvw,
    const float* __restrict__ W_pqr, const float* __restrict__ b_pqr,
    float* __restrict__ out)
{
    __shared__ float Ws[6 * HD];
    const int tid = threadIdx.x;
    for (int i = tid; i < 3 * HD; i += 256) Ws[i] = W_uvw[i];
    for (int i = tid; i < 3 * HD; i += 256) Ws[3 * HD + i] = W_pqr[i];
    __syncthreads();

    const int w = tid >> 6, L = tid & 63;
#pragma unroll
    for (int r = 0; r < 4; ++r) {
        const int t = blockIdx.x * 16 + w * 4 + r;
        const _Float16* hrow = hs16 + (size_t)t * HD;
        float acc[6] = {0.f, 0.f, 0.f, 0.f, 0.f, 0.f};
        for (int cidx = L; cidx < HD; cidx += 64) {
            float hval = (float)hrow[cidx];
#pragma unroll
            for (int j = 0; j < 6; ++j) acc[j] += hval * Ws[j * HD + cidx];
        }
#pragma unroll
        for (int j = 0; j < 6; ++j) {
#pragma unroll
            for (int d = 1; d < 64; d <<= 1)
                acc[j] += __shfl_xor(acc[j], d, 64);
        }
        if (L == 0) {
#pragma unroll
            for (int j = 0; j < 6; ++j)
                out[(size_t)t * 6 + j] =
                    acc[j] + (j < 3 ? b_uvw[j] : b_pqr[j - 3]);
        }
    }
}

extern "C" void kernel_launch(void* const* d_in, const int* in_sizes, int n_in,
                              void* d_out, int out_size, void* d_ws, size_t ws_size,
                              hipStream_t stream) {
    (void)in_sizes; (void)n_in; (void)out_size; (void)ws_size;

    const float* sa    = (const float*)d_in[0];
    const float* W_ih  = (const float*)d_in[1];
    const float* W_hh  = (const float*)d_in[2];
    const float* b_ih  = (const float*)d_in[3];
    const float* b_hh  = (const float*)d_in[4];
    const float* W_uvw = (const float*)d_in[5];
    const float* b_uvw = (const float*)d_in[6];
    const float* W_pqr = (const float*)d_in[7];
    const float* b_pqr = (const float*)d_in[8];
    float* out = (float*)d_out;

    // workspace: [hs16: 32 MB][hrep: NXCD*2*NSLOT*8 = 128 KB]
    char* ws = (char*)d_ws;
    _Float16* hs16 = (_Float16*)ws;
    unsigned long long* hrep =
        (unsigned long long*)(ws + (size_t)SEQ * HD * 2);

    // zero replicas: tag 0 == "h_0 = 0 is ready" in every copy
    hipMemsetAsync(hrep, 0, (size_t)NXCD * 2 * NSLOT * 8, stream);

    hipLaunchKernelGGL(lstm_persist, dim3(NBLK), dim3(NTHR), 0, stream,
                       sa, W_ih, W_hh, b_ih, b_hh, hrep, hs16);
    hipLaunchKernelGGL(out_proj_kernel, dim3(SEQ / 16), dim3(256), 0, stream,
                       hs16, W_uvw, b_uvw, W_pqr, b_pqr, out);
}